// Round 3
// baseline (199.089 us; speedup 1.0000x reference)
//
#include <hip/hip_runtime.h>
#include <math.h>

// PointLoss: fused masked reduction over B*H*W pixels -> scalar.
// v4: explicit depth-2 software pipeline. Each thread owns 4 quads; the
// streaming loads for quad i+1 are ISSUED before the compute of quad i,
// so every wave keeps ~128 cache lines in flight under its VALU burst
// (v1-v3 were phase-serial: load -> drain -> compute -> die, and all
// plateaued at ~1.35 TB/s effective BW regardless of TLP).

namespace {
constexpr int B_ = 64, H_ = 52, W_ = 720;
constexpr int HW_ = H_ * W_;           // 37440
constexpr int NPIX = B_ * HW_;         // 2396160
constexpr int QPI  = HW_ / 4;          // 9360 quads per image
constexpr int NQUAD = NPIX / 4;        // 599040
constexpr int NTHREADS = 256;
constexpr int QPT = 4;                 // quads per thread (pipeline depth fodder)
constexpr int NBLOCKS = NQUAD / (NTHREADS * QPT);   // 585
constexpr int TSTRIDE = NBLOCKS * NTHREADS;         // 149760 quads per sweep
constexpr float EPSF = 1e-8f;
constexpr float RAD2DEG = 57.29577951308232f;  // 180/pi
}
static_assert(NBLOCKS * NTHREADS * QPT == NQUAD, "grid must tile quads exactly");

struct Stream {
    float4 va, vb, vc;   // vertexmap quad (12 floats)
    float4 na, nb, nc;   // now_normal quad
    int4   mm;           // now_mask quad
    float4 cf;           // confidence quad
};

__global__ __launch_bounds__(NTHREADS) void pointloss_main(
    const float* __restrict__ v,      // vertexmap_proj   [B,H,W,3]
    const float* __restrict__ nrm,    // normalmap_proj   [B,H,W,3]
    const float* __restrict__ unc,    // uncertainty      [B,H,W]
    const float* __restrict__ nown,   // now_normalmap    [B,H,W,3]
    const float* __restrict__ conf,   // now_confidencemap[B,H,W]
    const float* __restrict__ lastn,  // last_normalmap   [B,H,W,3]
    const float* __restrict__ lastv,  // last_vertexmap   [B,H,W,3]
    const int*   __restrict__ nowm,   // now_maskmap      [B,H,W]
    const int*   __restrict__ lastm,  // last_maskmap     [B,H,W]
    float* __restrict__ partials)     // [NBLOCKS*5]
{
    float s_m0 = 0.f, s_fov = 0.f, s_m = 0.f, s_icp = 0.f, s_ang = 0.f;

    const float4* __restrict__ v4 = (const float4*)v;
    const float4* __restrict__ n4 = (const float4*)nown;
    const float4* __restrict__ r4 = (const float4*)nrm;
    const float4* __restrict__ u4 = (const float4*)unc;
    const int4*   __restrict__ m4 = (const int4*)nowm;
    const float4* __restrict__ c4 = (const float4*)conf;

    const int tid = blockIdx.x * NTHREADS + threadIdx.x;

    auto ld = [&](int q) {
        Stream s;
        s.va = v4[3*q+0]; s.vb = v4[3*q+1]; s.vc = v4[3*q+2];
        s.na = n4[3*q+0]; s.nb = n4[3*q+1]; s.nc = n4[3*q+2];
        s.mm = m4[q];
        s.cf = c4[q];
        return s;
    };

    // prologue: first quad's streams in flight
    Stream s = ld(tid);

    #pragma unroll
    for (int it = 0; it < QPT; ++it) {
        const int q = tid + it * TSTRIDE;

        // ---- issue NEXT quad's streaming loads before touching current ----
        Stream snext;
        if (it < QPT - 1) snext = ld(q + TSTRIDE);

        const int gbase = (q / QPI) * HW_;   // image base

        const float vx[4] = {s.va.x, s.va.w, s.vb.z, s.vc.y};
        const float vy[4] = {s.va.y, s.vb.x, s.vb.w, s.vc.z};
        const float vz[4] = {s.va.z, s.vb.y, s.vc.x, s.vc.w};
        const float ax[4] = {s.na.x, s.na.w, s.nb.z, s.nc.y};
        const float ay[4] = {s.na.y, s.nb.x, s.nb.w, s.nc.z};
        const float az[4] = {s.na.z, s.nb.y, s.nc.x, s.nc.w};
        const int   mk[4] = {s.mm.x, s.mm.y, s.mm.z, s.mm.w};
        const float cv[4] = {s.cf.x, s.cf.y, s.cf.z, s.cf.w};

        // ---- phase 1: projection math, fov loss, gather predicates ----
        bool g[4];
        int  gi[4];
        #pragma unroll
        for (int j = 0; j < 4; ++j) {
            const bool mask0 = (mk[j] > 0) &&
                ((fabsf(ax[j]) + fabsf(ay[j]) + fabsf(az[j])) != 0.0f);

            const float depth = sqrtf(vx[j]*vx[j] + vy[j]*vy[j] + vz[j]*vz[j] + EPSF);
            const float yaw   = atan2f(vy[j], vx[j]) * RAD2DEG;
            const float pitch = asinf(fminf(fmaxf(vz[j] / depth, -1.f), 1.f)) * RAD2DEG;
            const float px = (180.0f - yaw) * 2.0f;   // /DH with DH=0.5
            const float py = (3.0f - pitch) * 2.0f;   // /DV with DV=0.5

            if (mask0) {
                const float dx = px - fminf(fmaxf(px, 0.f), (float)(W_ - 1));
                const float dy = py - fminf(fmaxf(py, 0.f), (float)(H_ - 1));
                s_m0  += 1.0f;
                s_fov += dx*dx + dy*dy;
            }

            // jnp.round = round-half-even -> rintf (v_rndne_f32)
            const float prx = rintf(px), pry = rintf(py);
            const bool inb = (prx >= 0.f) && (prx < (float)W_) &&
                             (pry >= 0.f) && (pry < (float)H_);
            g[j]  = mask0 && inb && (cv[j] >= 0.5f);
            gi[j] = g[j] ? (gbase + (int)pry * W_ + (int)prx) : 0;
        }
        const bool anyg = g[0] | g[1] | g[2] | g[3];

        // ---- phase 2: batched gather-path loads ----
        float4 ra = {0,0,0,0}, rb = {0,0,0,0}, rc = {0,0,0,0}, uq = {0,0,0,0};
        if (anyg) {
            ra = r4[3*q+0]; rb = r4[3*q+1]; rc = r4[3*q+2];
            uq = u4[q];
        }
        float lx[4] = {0,0,0,0}, ly[4] = {0,0,0,0}, lz[4] = {0,0,0,0};
        float wx[4] = {0,0,0,0}, wy[4] = {0,0,0,0}, wz[4] = {0,0,0,0};
        int   lm[4] = {0,0,0,0};
        #pragma unroll
        for (int j = 0; j < 4; ++j) {
            if (g[j]) {
                const int gi3 = 3 * gi[j];
                lx[j] = lastn[gi3+0]; ly[j] = lastn[gi3+1]; lz[j] = lastn[gi3+2];
                lm[j] = lastm[gi[j]];
                wx[j] = lastv[gi3+0]; wy[j] = lastv[gi3+1]; wz[j] = lastv[gi3+2];
            }
        }

        const float nx[4] = {ra.x, ra.w, rb.z, rc.y};
        const float ny[4] = {ra.y, rb.x, rb.w, rc.z};
        const float nz[4] = {ra.z, rb.y, rc.x, rc.w};
        const float uu[4] = {uq.x, uq.y, uq.z, uq.w};

        // ---- phase 3: consume ----
        #pragma unroll
        for (int j = 0; j < 4; ++j) {
            if (g[j] && (lm[j] > 0) &&
                ((fabsf(lx[j]) + fabsf(ly[j]) + fabsf(lz[j])) != 0.f)) {
                const float r  = lx[j]*(vx[j]-wx[j]) + ly[j]*(vy[j]-wy[j])
                               + lz[j]*(vz[j]-wz[j]);
                const float dt = lx[j]*nx[j] + ly[j]*ny[j] + lz[j]*nz[j];
                const float den = (lx[j]*lx[j] + ly[j]*ly[j] + lz[j]*lz[j]) *
                                  (nx[j]*nx[j] + ny[j]*ny[j] + nz[j]*nz[j]) + EPSF;
                const float cosang = fabsf(dt) * rsqrtf(den);
                s_m   += 1.0f;
                s_icp += uu[j] * fabsf(r);
                s_ang += uu[j] * (1.0f - cosang);
            }
        }

        s = snext;   // rotate pipeline (SSA, no copies after unroll)
    }

    // wave64 shuffle reduce
    #pragma unroll
    for (int off = 32; off > 0; off >>= 1) {
        s_m0  += __shfl_down(s_m0,  off);
        s_fov += __shfl_down(s_fov, off);
        s_m   += __shfl_down(s_m,   off);
        s_icp += __shfl_down(s_icp, off);
        s_ang += __shfl_down(s_ang, off);
    }
    __shared__ float red[NTHREADS / 64][5];
    const int lane = threadIdx.x & 63;
    const int wv   = threadIdx.x >> 6;
    if (lane == 0) {
        red[wv][0] = s_m0;  red[wv][1] = s_fov; red[wv][2] = s_m;
        red[wv][3] = s_icp; red[wv][4] = s_ang;
    }
    __syncthreads();
    if (threadIdx.x == 0) {
        float t[5] = {0.f, 0.f, 0.f, 0.f, 0.f};
        for (int w2 = 0; w2 < NTHREADS / 64; ++w2)
            for (int c = 0; c < 5; ++c) t[c] += red[w2][c];
        float* o = partials + blockIdx.x * 5;
        for (int c = 0; c < 5; ++c) o[c] = t[c];
    }
}

__global__ __launch_bounds__(256) void pointloss_finalize(
    const float* __restrict__ partials,
    const float* __restrict__ sx,
    const float* __restrict__ sq,
    float* __restrict__ out)
{
    double a0 = 0, a1 = 0, a2 = 0, a3 = 0, a4 = 0;
    for (int i = threadIdx.x; i < NBLOCKS; i += 256) {
        const float* pp = partials + i * 5;
        a0 += (double)pp[0]; a1 += (double)pp[1]; a2 += (double)pp[2];
        a3 += (double)pp[3]; a4 += (double)pp[4];
    }
    #pragma unroll
    for (int off = 32; off > 0; off >>= 1) {
        a0 += __shfl_down(a0, off);
        a1 += __shfl_down(a1, off);
        a2 += __shfl_down(a2, off);
        a3 += __shfl_down(a3, off);
        a4 += __shfl_down(a4, off);
    }
    __shared__ double red[4][5];
    const int lane = threadIdx.x & 63;
    const int wv   = threadIdx.x >> 6;
    if (lane == 0) {
        red[wv][0] = a0; red[wv][1] = a1; red[wv][2] = a2;
        red[wv][3] = a3; red[wv][4] = a4;
    }
    __syncthreads();
    if (threadIdx.x == 0) {
        double t[5] = {0, 0, 0, 0, 0};
        for (int w2 = 0; w2 < 4; ++w2)
            for (int c = 0; c < 5; ++c) t[c] += red[w2][c];
        const double n0 = fmax(t[0], 1.0);
        const double n  = fmax(t[2], 1.0);
        const double sx0 = (double)sx[0], sq0 = (double)sq[0];
        const double total = exp(-sx0) * (t[3] / n) + sx0
                           + exp(-sq0) * (t[4] / n) + sq0
                           + t[1] / n0;   // LAMDA = 1, ANGRATE = 1
        out[0] = (float)total;
    }
}

extern "C" void kernel_launch(void* const* d_in, const int* in_sizes, int n_in,
                              void* d_out, int out_size, void* d_ws, size_t ws_size,
                              hipStream_t stream) {
    const float* v     = (const float*)d_in[0];
    const float* nrm   = (const float*)d_in[1];
    const float* unc   = (const float*)d_in[2];
    const float* nown  = (const float*)d_in[3];
    const float* conf  = (const float*)d_in[4];
    const float* lastn = (const float*)d_in[5];
    const float* lastv = (const float*)d_in[6];
    const float* sx    = (const float*)d_in[7];
    const float* sq    = (const float*)d_in[8];
    const int*   nowm  = (const int*)d_in[9];
    const int*   lastm = (const int*)d_in[10];

    float* partials = (float*)d_ws;  // NBLOCKS*5 floats = 11.7 KB

    pointloss_main<<<NBLOCKS, NTHREADS, 0, stream>>>(
        v, nrm, unc, nown, conf, lastn, lastv, nowm, lastm, partials);
    pointloss_finalize<<<1, 256, 0, stream>>>(partials, sx, sq, (float*)d_out);
}

// Round 4
// 197.351 us; speedup vs baseline: 1.0088x; 1.0088x over previous
//
#include <hip/hip_runtime.h>
#include <math.h>

// PointLoss: fused masked reduction over B*H*W pixels -> scalar.
// v5: wide-batch. Each thread owns TWO quads; all 16 streaming dwordx4 are
// issued before any compute, and BOTH quads' gather loads are issued in one
// batch before a single drain point. Combines v3's wave pool (1170 blocks,
// 4.6 blocks/CU) with 2x the per-wave MLP of v4 in BOTH phases.
// (v1-v4 post-mortems: throughput ~ waves x in-flight-requests; every prior
// version raised one factor and lowered the other -> all ~1.35 TB/s.)

namespace {
constexpr int B_ = 64, H_ = 52, W_ = 720;
constexpr int HW_ = H_ * W_;           // 37440
constexpr int NPIX = B_ * HW_;         // 2396160
constexpr int QPI  = HW_ / 4;          // 9360 quads per image
constexpr int NQUAD = NPIX / 4;        // 599040
constexpr int NTHREADS = 256;
constexpr int QPT = 2;                 // quads per thread (wide batch)
constexpr int NBLOCKS = NQUAD / (NTHREADS * QPT);   // 1170
constexpr int TSTRIDE = NBLOCKS * NTHREADS;         // 299520
constexpr float EPSF = 1e-8f;
constexpr float RAD2DEG = 57.29577951308232f;  // 180/pi
}
static_assert(NBLOCKS * NTHREADS * QPT == NQUAD, "grid must tile quads exactly");

struct Stream {
    float4 va, vb, vc;   // vertexmap quad (12 floats)
    float4 na, nb, nc;   // now_normal quad
    int4   mm;           // now_mask quad
    float4 cf;           // confidence quad
};

struct Quad {            // phase-1 outputs needed later
    float vx[4], vy[4], vz[4];
    bool  g[4];
    int   gi[4];
    bool  anyg;
};

struct Gath {            // phase-2 gathered operands
    float lx[4], ly[4], lz[4];
    float wx[4], wy[4], wz[4];
    float nx[4], ny[4], nz[4];
    float uu[4];
    int   lm[4];
};

__global__ __launch_bounds__(NTHREADS) void pointloss_main(
    const float* __restrict__ v,      // vertexmap_proj   [B,H,W,3]
    const float* __restrict__ nrm,    // normalmap_proj   [B,H,W,3]
    const float* __restrict__ unc,    // uncertainty      [B,H,W]
    const float* __restrict__ nown,   // now_normalmap    [B,H,W,3]
    const float* __restrict__ conf,   // now_confidencemap[B,H,W]
    const float* __restrict__ lastn,  // last_normalmap   [B,H,W,3]
    const float* __restrict__ lastv,  // last_vertexmap   [B,H,W,3]
    const int*   __restrict__ nowm,   // now_maskmap      [B,H,W]
    const int*   __restrict__ lastm,  // last_maskmap     [B,H,W]
    float* __restrict__ partials)     // [NBLOCKS*5]
{
    float s_m0 = 0.f, s_fov = 0.f, s_m = 0.f, s_icp = 0.f, s_ang = 0.f;

    const float4* __restrict__ v4 = (const float4*)v;
    const float4* __restrict__ n4 = (const float4*)nown;
    const float4* __restrict__ r4 = (const float4*)nrm;
    const float4* __restrict__ u4 = (const float4*)unc;
    const int4*   __restrict__ m4 = (const int4*)nowm;
    const float4* __restrict__ c4 = (const float4*)conf;

    const int tid = blockIdx.x * NTHREADS + threadIdx.x;
    const int q0 = tid;
    const int q1 = tid + TSTRIDE;

    auto ld = [&](int q) {
        Stream s;
        s.va = v4[3*q+0]; s.vb = v4[3*q+1]; s.vc = v4[3*q+2];
        s.na = n4[3*q+0]; s.nb = n4[3*q+1]; s.nc = n4[3*q+2];
        s.mm = m4[q];
        s.cf = c4[q];
        return s;
    };

    // ---- issue ALL streaming loads (16 dwordx4) before any compute ----
    const Stream S0 = ld(q0);
    const Stream S1 = ld(q1);

    auto phase1 = [&](const Stream& s, int q, Quad& Q) {
        const int gbase = (q / QPI) * HW_;   // image base
        const float vx[4] = {s.va.x, s.va.w, s.vb.z, s.vc.y};
        const float vy[4] = {s.va.y, s.vb.x, s.vb.w, s.vc.z};
        const float vz[4] = {s.va.z, s.vb.y, s.vc.x, s.vc.w};
        const float ax[4] = {s.na.x, s.na.w, s.nb.z, s.nc.y};
        const float ay[4] = {s.na.y, s.nb.x, s.nb.w, s.nc.z};
        const float az[4] = {s.na.z, s.nb.y, s.nc.x, s.nc.w};
        const int   mk[4] = {s.mm.x, s.mm.y, s.mm.z, s.mm.w};
        const float cv[4] = {s.cf.x, s.cf.y, s.cf.z, s.cf.w};

        #pragma unroll
        for (int j = 0; j < 4; ++j) {
            const bool mask0 = (mk[j] > 0) &&
                ((fabsf(ax[j]) + fabsf(ay[j]) + fabsf(az[j])) != 0.0f);

            const float depth = sqrtf(vx[j]*vx[j] + vy[j]*vy[j] + vz[j]*vz[j] + EPSF);
            const float yaw   = atan2f(vy[j], vx[j]) * RAD2DEG;
            const float pitch = asinf(fminf(fmaxf(vz[j] / depth, -1.f), 1.f)) * RAD2DEG;
            const float px = (180.0f - yaw) * 2.0f;   // /DH with DH=0.5
            const float py = (3.0f - pitch) * 2.0f;   // /DV with DV=0.5

            if (mask0) {
                const float dx = px - fminf(fmaxf(px, 0.f), (float)(W_ - 1));
                const float dy = py - fminf(fmaxf(py, 0.f), (float)(H_ - 1));
                s_m0  += 1.0f;
                s_fov += dx*dx + dy*dy;
            }

            // jnp.round = round-half-even -> rintf (v_rndne_f32)
            const float prx = rintf(px), pry = rintf(py);
            const bool inb = (prx >= 0.f) && (prx < (float)W_) &&
                             (pry >= 0.f) && (pry < (float)H_);
            Q.g[j]  = mask0 && inb && (cv[j] >= 0.5f);
            Q.gi[j] = Q.g[j] ? (gbase + (int)pry * W_ + (int)prx) : 0;
            Q.vx[j] = vx[j]; Q.vy[j] = vy[j]; Q.vz[j] = vz[j];
        }
        Q.anyg = Q.g[0] | Q.g[1] | Q.g[2] | Q.g[3];
    };

    Quad Q0, Q1;
    phase1(S0, q0, Q0);
    phase1(S1, q1, Q1);

    // ---- issue BOTH quads' gather-path loads in one batch ----
    auto gather = [&](const Quad& Q, int q, Gath& G) {
        float4 ra = {0,0,0,0}, rb = {0,0,0,0}, rc = {0,0,0,0}, uq = {0,0,0,0};
        if (Q.anyg) {
            ra = r4[3*q+0]; rb = r4[3*q+1]; rc = r4[3*q+2];
            uq = u4[q];
        }
        #pragma unroll
        for (int j = 0; j < 4; ++j) {
            G.lx[j] = 0.f; G.ly[j] = 0.f; G.lz[j] = 0.f;
            G.wx[j] = 0.f; G.wy[j] = 0.f; G.wz[j] = 0.f;
            G.lm[j] = 0;
            if (Q.g[j]) {
                const int gi3 = 3 * Q.gi[j];
                G.lx[j] = lastn[gi3+0]; G.ly[j] = lastn[gi3+1]; G.lz[j] = lastn[gi3+2];
                G.lm[j] = lastm[Q.gi[j]];
                G.wx[j] = lastv[gi3+0]; G.wy[j] = lastv[gi3+1]; G.wz[j] = lastv[gi3+2];
            }
        }
        G.nx[0]=ra.x; G.nx[1]=ra.w; G.nx[2]=rb.z; G.nx[3]=rc.y;
        G.ny[0]=ra.y; G.ny[1]=rb.x; G.ny[2]=rb.w; G.ny[3]=rc.z;
        G.nz[0]=ra.z; G.nz[1]=rb.y; G.nz[2]=rc.x; G.nz[3]=rc.w;
        G.uu[0]=uq.x; G.uu[1]=uq.y; G.uu[2]=uq.z; G.uu[3]=uq.w;
    };

    Gath G0, G1;
    gather(Q0, q0, G0);
    gather(Q1, q1, G1);

    // ---- consume both quads behind one drain point ----
    auto consume = [&](const Quad& Q, const Gath& G) {
        #pragma unroll
        for (int j = 0; j < 4; ++j) {
            if (Q.g[j] && (G.lm[j] > 0) &&
                ((fabsf(G.lx[j]) + fabsf(G.ly[j]) + fabsf(G.lz[j])) != 0.f)) {
                const float r  = G.lx[j]*(Q.vx[j]-G.wx[j]) + G.ly[j]*(Q.vy[j]-G.wy[j])
                               + G.lz[j]*(Q.vz[j]-G.wz[j]);
                const float dt = G.lx[j]*G.nx[j] + G.ly[j]*G.ny[j] + G.lz[j]*G.nz[j];
                const float den = (G.lx[j]*G.lx[j] + G.ly[j]*G.ly[j] + G.lz[j]*G.lz[j]) *
                                  (G.nx[j]*G.nx[j] + G.ny[j]*G.ny[j] + G.nz[j]*G.nz[j]) + EPSF;
                const float cosang = fabsf(dt) * rsqrtf(den);
                s_m   += 1.0f;
                s_icp += G.uu[j] * fabsf(r);
                s_ang += G.uu[j] * (1.0f - cosang);
            }
        }
    };

    consume(Q0, G0);
    consume(Q1, G1);

    // wave64 shuffle reduce
    #pragma unroll
    for (int off = 32; off > 0; off >>= 1) {
        s_m0  += __shfl_down(s_m0,  off);
        s_fov += __shfl_down(s_fov, off);
        s_m   += __shfl_down(s_m,   off);
        s_icp += __shfl_down(s_icp, off);
        s_ang += __shfl_down(s_ang, off);
    }
    __shared__ float red[NTHREADS / 64][5];
    const int lane = threadIdx.x & 63;
    const int wv   = threadIdx.x >> 6;
    if (lane == 0) {
        red[wv][0] = s_m0;  red[wv][1] = s_fov; red[wv][2] = s_m;
        red[wv][3] = s_icp; red[wv][4] = s_ang;
    }
    __syncthreads();
    if (threadIdx.x == 0) {
        float t[5] = {0.f, 0.f, 0.f, 0.f, 0.f};
        for (int w2 = 0; w2 < NTHREADS / 64; ++w2)
            for (int c = 0; c < 5; ++c) t[c] += red[w2][c];
        float* o = partials + blockIdx.x * 5;
        for (int c = 0; c < 5; ++c) o[c] = t[c];
    }
}

__global__ __launch_bounds__(256) void pointloss_finalize(
    const float* __restrict__ partials,
    const float* __restrict__ sx,
    const float* __restrict__ sq,
    float* __restrict__ out)
{
    double a0 = 0, a1 = 0, a2 = 0, a3 = 0, a4 = 0;
    for (int i = threadIdx.x; i < NBLOCKS; i += 256) {
        const float* pp = partials + i * 5;
        a0 += (double)pp[0]; a1 += (double)pp[1]; a2 += (double)pp[2];
        a3 += (double)pp[3]; a4 += (double)pp[4];
    }
    #pragma unroll
    for (int off = 32; off > 0; off >>= 1) {
        a0 += __shfl_down(a0, off);
        a1 += __shfl_down(a1, off);
        a2 += __shfl_down(a2, off);
        a3 += __shfl_down(a3, off);
        a4 += __shfl_down(a4, off);
    }
    __shared__ double red[4][5];
    const int lane = threadIdx.x & 63;
    const int wv   = threadIdx.x >> 6;
    if (lane == 0) {
        red[wv][0] = a0; red[wv][1] = a1; red[wv][2] = a2;
        red[wv][3] = a3; red[wv][4] = a4;
    }
    __syncthreads();
    if (threadIdx.x == 0) {
        double t[5] = {0, 0, 0, 0, 0};
        for (int w2 = 0; w2 < 4; ++w2)
            for (int c = 0; c < 5; ++c) t[c] += red[w2][c];
        const double n0 = fmax(t[0], 1.0);
        const double n  = fmax(t[2], 1.0);
        const double sx0 = (double)sx[0], sq0 = (double)sq[0];
        const double total = exp(-sx0) * (t[3] / n) + sx0
                           + exp(-sq0) * (t[4] / n) + sq0
                           + t[1] / n0;   // LAMDA = 1, ANGRATE = 1
        out[0] = (float)total;
    }
}

extern "C" void kernel_launch(void* const* d_in, const int* in_sizes, int n_in,
                              void* d_out, int out_size, void* d_ws, size_t ws_size,
                              hipStream_t stream) {
    const float* v     = (const float*)d_in[0];
    const float* nrm   = (const float*)d_in[1];
    const float* unc   = (const float*)d_in[2];
    const float* nown  = (const float*)d_in[3];
    const float* conf  = (const float*)d_in[4];
    const float* lastn = (const float*)d_in[5];
    const float* lastv = (const float*)d_in[6];
    const float* sx    = (const float*)d_in[7];
    const float* sq    = (const float*)d_in[8];
    const int*   nowm  = (const int*)d_in[9];
    const int*   lastm = (const int*)d_in[10];

    float* partials = (float*)d_ws;  // NBLOCKS*5 floats = 23.4 KB

    pointloss_main<<<NBLOCKS, NTHREADS, 0, stream>>>(
        v, nrm, unc, nown, conf, lastn, lastv, nowm, lastm, partials);
    pointloss_finalize<<<1, 256, 0, stream>>>(partials, sx, sq, (float*)d_out);
}